// Round 1
// baseline (421.278 us; speedup 1.0000x reference)
//
#include <hip/hip_runtime.h>

#define N_NODES 50000
#define N_EDGES 800000
#define IN_CH   128
#define HID     64

// ---------------- CSR build ----------------

__global__ __launch_bounds__(256) void count_deg(const int* __restrict__ dst,
                                                 int* __restrict__ deg) {
  int e = blockIdx.x * 256 + threadIdx.x;
  if (e < N_EDGES) atomicAdd(&deg[dst[e]], 1);
}

// single-block exclusive scan of deg[N] -> rowstart[N+1]
__global__ __launch_bounds__(1024) void scan_deg(const int* __restrict__ deg,
                                                 int* __restrict__ rowstart) {
  __shared__ int wsum[16];
  __shared__ int s_carry;
  int t = threadIdx.x;
  int lane = t & 63, wid = t >> 6;
  if (t == 0) s_carry = 0;
  __syncthreads();
  for (int base = 0; base < N_NODES; base += 1024) {
    int i = base + t;
    int orig = (i < N_NODES) ? deg[i] : 0;
    int v = orig;
#pragma unroll
    for (int d = 1; d < 64; d <<= 1) {
      int u = __shfl_up(v, d);
      if (lane >= d) v += u;
    }
    if (lane == 63) wsum[wid] = v;
    __syncthreads();
    if (wid == 0) {
      int w = (lane < 16) ? wsum[lane] : 0;
#pragma unroll
      for (int d = 1; d < 16; d <<= 1) {
        int u = __shfl_up(w, d);
        if (lane >= d) w += u;
      }
      if (lane < 16) wsum[lane] = w;
    }
    __syncthreads();
    int waveoff = (wid > 0) ? wsum[wid - 1] : 0;
    int incl = v + waveoff + s_carry;
    if (i < N_NODES) rowstart[i] = incl - orig;
    __syncthreads();
    if (t == 1023) s_carry = incl;
    __syncthreads();
  }
  if (t == 0) rowstart[N_NODES] = s_carry;
}

__global__ __launch_bounds__(256) void scatter_edges(const int* __restrict__ src,
                                                     const int* __restrict__ dst,
                                                     const int* __restrict__ rowstart,
                                                     int* __restrict__ cursor,
                                                     int* __restrict__ csr_src) {
  int e = blockIdx.x * 256 + threadIdx.x;
  if (e < N_EDGES) {
    int d = dst[e];
    int pos = atomicAdd(&cursor[d], 1);
    csr_src[rowstart[d] + pos] = src[e];
  }
}

// ---------------- dual GEMM: out[N,128] = [H@Wa^T | H@Wb^T] ----------------
// Wa, Wb are [64, K] row-major with row stride ldW. H is [N, K] with row stride ldH.

__global__ __launch_bounds__(256)
void gemm_dual(const float* __restrict__ H, int ldH, int K,
               const float* __restrict__ Wa, const float* __restrict__ Wb, int ldW,
               float* __restrict__ out) {
  __shared__ float Hs[64][33];
  __shared__ float Ws[32][132];
  int t = threadIdx.x;
  int r0 = blockIdx.x * 64;
  int tx = t & 15;        // cols tx*8 .. tx*8+7
  int ty = t >> 4;        // rows ty*4 .. ty*4+3

  float acc[4][8];
#pragma unroll
  for (int i = 0; i < 4; ++i)
#pragma unroll
    for (int j = 0; j < 8; ++j) acc[i][j] = 0.f;

  int hrow = t >> 2;
  int hkk  = (t & 3) * 8;
  int wc   = t & 127;
  int wkk  = (t >> 7) * 16;
  const float* wbase = (wc < 64) ? (Wa + (size_t)wc * ldW)
                                 : (Wb + (size_t)(wc - 64) * ldW);

  for (int k0 = 0; k0 < K; k0 += 32) {
    float4 h0, h1;
    int gr = r0 + hrow;
    if (gr < N_NODES) {
      const float* p = H + (size_t)gr * ldH + k0 + hkk;
      h0 = *(const float4*)p;
      h1 = *(const float4*)(p + 4);
    } else {
      h0 = make_float4(0.f, 0.f, 0.f, 0.f);
      h1 = h0;
    }
    const float* wp = wbase + k0 + wkk;
    float4 w0 = *(const float4*)(wp + 0);
    float4 w1 = *(const float4*)(wp + 4);
    float4 w2 = *(const float4*)(wp + 8);
    float4 w3 = *(const float4*)(wp + 12);

    __syncthreads();  // previous iteration's reads done
    Hs[hrow][hkk + 0] = h0.x; Hs[hrow][hkk + 1] = h0.y;
    Hs[hrow][hkk + 2] = h0.z; Hs[hrow][hkk + 3] = h0.w;
    Hs[hrow][hkk + 4] = h1.x; Hs[hrow][hkk + 5] = h1.y;
    Hs[hrow][hkk + 6] = h1.z; Hs[hrow][hkk + 7] = h1.w;
    Ws[wkk +  0][wc] = w0.x; Ws[wkk +  1][wc] = w0.y;
    Ws[wkk +  2][wc] = w0.z; Ws[wkk +  3][wc] = w0.w;
    Ws[wkk +  4][wc] = w1.x; Ws[wkk +  5][wc] = w1.y;
    Ws[wkk +  6][wc] = w1.z; Ws[wkk +  7][wc] = w1.w;
    Ws[wkk +  8][wc] = w2.x; Ws[wkk +  9][wc] = w2.y;
    Ws[wkk + 10][wc] = w2.z; Ws[wkk + 11][wc] = w2.w;
    Ws[wkk + 12][wc] = w3.x; Ws[wkk + 13][wc] = w3.y;
    Ws[wkk + 14][wc] = w3.z; Ws[wkk + 15][wc] = w3.w;
    __syncthreads();

#pragma unroll
    for (int k = 0; k < 32; ++k) {
      float a0 = Hs[ty * 4 + 0][k];
      float a1 = Hs[ty * 4 + 1][k];
      float a2 = Hs[ty * 4 + 2][k];
      float a3 = Hs[ty * 4 + 3][k];
      float4 b0 = *(const float4*)&Ws[k][tx * 8];
      float4 b1 = *(const float4*)&Ws[k][tx * 8 + 4];
      acc[0][0] += a0 * b0.x; acc[0][1] += a0 * b0.y; acc[0][2] += a0 * b0.z; acc[0][3] += a0 * b0.w;
      acc[0][4] += a0 * b1.x; acc[0][5] += a0 * b1.y; acc[0][6] += a0 * b1.z; acc[0][7] += a0 * b1.w;
      acc[1][0] += a1 * b0.x; acc[1][1] += a1 * b0.y; acc[1][2] += a1 * b0.z; acc[1][3] += a1 * b0.w;
      acc[1][4] += a1 * b1.x; acc[1][5] += a1 * b1.y; acc[1][6] += a1 * b1.z; acc[1][7] += a1 * b1.w;
      acc[2][0] += a2 * b0.x; acc[2][1] += a2 * b0.y; acc[2][2] += a2 * b0.z; acc[2][3] += a2 * b0.w;
      acc[2][4] += a2 * b1.x; acc[2][5] += a2 * b1.y; acc[2][6] += a2 * b1.z; acc[2][7] += a2 * b1.w;
      acc[3][0] += a3 * b0.x; acc[3][1] += a3 * b0.y; acc[3][2] += a3 * b0.z; acc[3][3] += a3 * b0.w;
      acc[3][4] += a3 * b1.x; acc[3][5] += a3 * b1.y; acc[3][6] += a3 * b1.z; acc[3][7] += a3 * b1.w;
    }
  }

#pragma unroll
  for (int i = 0; i < 4; ++i) {
    int row = r0 + ty * 4 + i;
    if (row < N_NODES) {
      float* o = out + (size_t)row * 128 + tx * 8;
      *(float4*)(o + 0) = make_float4(acc[i][0], acc[i][1], acc[i][2], acc[i][3]);
      *(float4*)(o + 4) = make_float4(acc[i][4], acc[i][5], acc[i][6], acc[i][7]);
    }
  }
}

// ---------------- aggregation (one wave per node, lane = feature) ----------------
// yr: [N,128], cols 0..63 = h@Wl^T, cols 64..127 = h@Wr^T.
// out = relu(segsum(y[src])/max(deg,1) + bl + r), written to xcat (ld 192).

__global__ __launch_bounds__(256)
void agg_fuse(const float* __restrict__ yr, const int* __restrict__ rowstart,
              const int* __restrict__ csr_src, const float* __restrict__ bl,
              float* __restrict__ out) {
  int w = (blockIdx.x * 256 + threadIdx.x) >> 6;
  int lane = threadIdx.x & 63;
  if (w >= N_NODES) return;
  int beg = rowstart[w], end = rowstart[w + 1];
  float s = 0.f;
  int i = beg;
  for (; i + 4 <= end; i += 4) {
    int s0 = csr_src[i + 0];
    int s1 = csr_src[i + 1];
    int s2 = csr_src[i + 2];
    int s3 = csr_src[i + 3];
    float v0 = yr[(size_t)s0 * 128 + lane];
    float v1 = yr[(size_t)s1 * 128 + lane];
    float v2 = yr[(size_t)s2 * 128 + lane];
    float v3 = yr[(size_t)s3 * 128 + lane];
    s += (v0 + v1) + (v2 + v3);
  }
  for (; i < end; ++i) s += yr[(size_t)csr_src[i] * 128 + lane];
  float deg = (float)(end - beg);
  float inv = deg > 0.f ? 1.0f / deg : 1.0f;
  float h = s * inv + bl[lane] + yr[(size_t)w * 128 + 64 + lane];
  out[(size_t)w * 192 + lane] = fmaxf(h, 0.f);
}

// ---------------- edge MLP: out[e] = relu(P[src]+Q[dst]+bm1) . wm2 + bm2 ----------------

__global__ __launch_bounds__(256)
void edge_mlp(const int* __restrict__ src, const int* __restrict__ dst,
              const float* __restrict__ PQ, const float* __restrict__ bm1,
              const float* __restrict__ wm2, const float* __restrict__ bm2v,
              float* __restrict__ out) {
  int t = threadIdx.x;
  int g = t >> 4, l = t & 15;
  int e = blockIdx.x * 16 + g;
  if (e >= N_EDGES) return;
  int s = src[e], d = dst[e];
  float4 p = *(const float4*)&PQ[(size_t)s * 128 + l * 4];
  float4 q = *(const float4*)&PQ[(size_t)d * 128 + 64 + l * 4];
  float4 b = *(const float4*)&bm1[l * 4];
  float4 w = *(const float4*)&wm2[l * 4];
  float h0 = fmaxf(p.x + q.x + b.x, 0.f);
  float h1 = fmaxf(p.y + q.y + b.y, 0.f);
  float h2 = fmaxf(p.z + q.z + b.z, 0.f);
  float h3 = fmaxf(p.w + q.w + b.w, 0.f);
  float part = h0 * w.x + h1 * w.y + h2 * w.z + h3 * w.w;
#pragma unroll
  for (int m = 1; m < 16; m <<= 1) part += __shfl_xor(part, m);
  if (l == 0) out[e] = part + bm2v[0];
}

// ---------------- launch ----------------

extern "C" void kernel_launch(void* const* d_in, const int* in_sizes, int n_in,
                              void* d_out, int out_size, void* d_ws, size_t ws_size,
                              hipStream_t stream) {
  (void)in_sizes; (void)n_in; (void)out_size; (void)ws_size;
  const float* x   = (const float*)d_in[0];
  const int*   src = (const int*)d_in[1];
  const int*   dst = (const int*)d_in[2];
  const float* Wl0 = (const float*)d_in[3];
  const float* bl0 = (const float*)d_in[4];
  const float* Wr0 = (const float*)d_in[5];
  const float* Wl1 = (const float*)d_in[6];
  const float* bl1 = (const float*)d_in[7];
  const float* Wr1 = (const float*)d_in[8];
  const float* Wl2 = (const float*)d_in[9];
  const float* bl2 = (const float*)d_in[10];
  const float* Wr2 = (const float*)d_in[11];
  const float* Wm1 = (const float*)d_in[12];
  const float* bm1 = (const float*)d_in[13];
  const float* Wm2 = (const float*)d_in[14];
  const float* bm2 = (const float*)d_in[15];
  float* out = (float*)d_out;

  char* ws = (char*)d_ws;
  size_t off = 0;
  auto take = [&](size_t bytes) {
    char* p = ws + off;
    off = (off + bytes + 255) & ~(size_t)255;
    return p;
  };
  int*   deg      = (int*)take((size_t)N_NODES * 4);
  int*   cursor   = (int*)take((size_t)N_NODES * 4);
  int*   rowstart = (int*)take((size_t)(N_NODES + 1) * 4);
  int*   csr_src  = (int*)take((size_t)N_EDGES * 4);
  float* xcat     = (float*)take((size_t)N_NODES * 192 * 4);
  float* yr       = (float*)take((size_t)N_NODES * 128 * 4);

  hipMemsetAsync(deg, 0, (size_t)N_NODES * 4, stream);
  hipMemsetAsync(cursor, 0, (size_t)N_NODES * 4, stream);

  count_deg<<<(N_EDGES + 255) / 256, 256, 0, stream>>>(dst, deg);
  scan_deg<<<1, 1024, 0, stream>>>(deg, rowstart);
  scatter_edges<<<(N_EDGES + 255) / 256, 256, 0, stream>>>(src, dst, rowstart, cursor, csr_src);

  int gemm_grid = (N_NODES + 63) / 64;
  // layer 0: input x [N,128]
  gemm_dual<<<gemm_grid, 256, 0, stream>>>(x, IN_CH, IN_CH, Wl0, Wr0, IN_CH, yr);
  agg_fuse<<<(N_NODES * 64) / 256, 256, 0, stream>>>(yr, rowstart, csr_src, bl0, xcat + 0);
  // layer 1: input xcat cols 0..63
  gemm_dual<<<gemm_grid, 256, 0, stream>>>(xcat + 0, 192, HID, Wl1, Wr1, HID, yr);
  agg_fuse<<<(N_NODES * 64) / 256, 256, 0, stream>>>(yr, rowstart, csr_src, bl1, xcat + 64);
  // layer 2: input xcat cols 64..127
  gemm_dual<<<gemm_grid, 256, 0, stream>>>(xcat + 64, 192, HID, Wl2, Wr2, HID, yr);
  agg_fuse<<<(N_NODES * 64) / 256, 256, 0, stream>>>(yr, rowstart, csr_src, bl2, xcat + 128);
  // P|Q = xcat @ [Wm1[:, :192] | Wm1[:, 192:]]^T  (reuse yr)
  gemm_dual<<<gemm_grid, 256, 0, stream>>>(xcat, 192, 192, Wm1, Wm1 + 192, 384, yr);
  edge_mlp<<<(N_EDGES + 15) / 16, 256, 0, stream>>>(src, dst, yr, bm1, Wm2, bm2, out);
}

// Round 2
// 396.734 us; speedup vs baseline: 1.0619x; 1.0619x over previous
//
#include <hip/hip_runtime.h>

#define N_NODES 50000
#define N_EDGES 800000
#define IN_CH   128
#define HID     64
#define SCAN_BLOCKS ((N_NODES + 255) / 256)   // 196

// ---------------- bf16 helpers ----------------

__device__ inline float bfraw(unsigned int bits) {
  float f; __builtin_memcpy(&f, &bits, 4); return f;
}
__device__ inline float bf2f(unsigned short u) {
  return bfraw(((unsigned int)u) << 16);
}
__device__ inline unsigned short f2bf(float f) {
  unsigned int x; __builtin_memcpy(&x, &f, 4);
  return (unsigned short)((x + 0x7FFFu + ((x >> 16) & 1u)) >> 16);
}

// ---------------- CSR build ----------------

__global__ __launch_bounds__(256) void count_deg(const int* __restrict__ dst,
                                                 int* __restrict__ deg) {
  int e = blockIdx.x * 256 + threadIdx.x;
  if (e < N_EDGES) atomicAdd(&deg[dst[e]], 1);
}

// block sums of deg, 256 elems per block
__global__ __launch_bounds__(256) void k_blocksum(const int* __restrict__ deg,
                                                  int* __restrict__ bsum) {
  int t = threadIdx.x, lane = t & 63, wid = t >> 6;
  int i = blockIdx.x * 256 + t;
  int v = (i < N_NODES) ? deg[i] : 0;
#pragma unroll
  for (int d = 32; d > 0; d >>= 1) v += __shfl_down(v, d);
  __shared__ int ws[4];
  if (lane == 0) ws[wid] = v;
  __syncthreads();
  if (t == 0) bsum[blockIdx.x] = ws[0] + ws[1] + ws[2] + ws[3];
}

// single block: exclusive scan of bsum[SCAN_BLOCKS] -> boff; rowstart[N]=E
__global__ __launch_bounds__(256) void k_scanb(const int* __restrict__ bsum,
                                               int* __restrict__ boff,
                                               int* __restrict__ rowstart) {
  int t = threadIdx.x, lane = t & 63, wid = t >> 6;
  int v = (t < SCAN_BLOCKS) ? bsum[t] : 0;
  int orig = v;
#pragma unroll
  for (int d = 1; d < 64; d <<= 1) {
    int u = __shfl_up(v, d);
    if (lane >= d) v += u;
  }
  __shared__ int ws[4];
  if (lane == 63) ws[wid] = v;
  __syncthreads();
  int off = 0;
  for (int j = 0; j < wid; ++j) off += ws[j];
  if (t < SCAN_BLOCKS) boff[t] = v - orig + off;
  if (t == 0) rowstart[N_NODES] = N_EDGES;
}

// per-block exclusive scan + block offset -> rowstart
__global__ __launch_bounds__(256) void k_local(const int* __restrict__ deg,
                                               const int* __restrict__ boff,
                                               int* __restrict__ rowstart) {
  int t = threadIdx.x, lane = t & 63, wid = t >> 6;
  int i = blockIdx.x * 256 + t;
  int orig = (i < N_NODES) ? deg[i] : 0;
  int v = orig;
#pragma unroll
  for (int d = 1; d < 64; d <<= 1) {
    int u = __shfl_up(v, d);
    if (lane >= d) v += u;
  }
  __shared__ int ws[4];
  if (lane == 63) ws[wid] = v;
  __syncthreads();
  int off = boff[blockIdx.x];
  for (int j = 0; j < wid; ++j) off += ws[j];
  if (i < N_NODES) rowstart[i] = v - orig + off;
}

__global__ __launch_bounds__(256) void scatter_edges(const int* __restrict__ src,
                                                     const int* __restrict__ dst,
                                                     const int* __restrict__ rowstart,
                                                     int* __restrict__ cursor,
                                                     int* __restrict__ csr_src,
                                                     int* __restrict__ csr_eid) {
  int e = blockIdx.x * 256 + threadIdx.x;
  if (e < N_EDGES) {
    int d = dst[e];
    int pos = atomicAdd(&cursor[d], 1);
    int slot = rowstart[d] + pos;
    csr_src[slot] = src[e];
    csr_eid[slot] = e;
  }
}

// ---------------- dual GEMM ----------------
// outA[N,64] (bf16)      = H @ Wa^T            (the part that gets neighbor-aggregated / gathered)
// outB[N,64] (fp32)      = H @ Wb^T + bias     (root path / Q path, bias folded)

__global__ __launch_bounds__(256)
void gemm_dual(const float* __restrict__ H, int ldH, int K,
               const float* __restrict__ Wa, const float* __restrict__ Wb, int ldW,
               const float* __restrict__ bias,
               unsigned short* __restrict__ outA, float* __restrict__ outB) {
  __shared__ float Hs[64][33];
  __shared__ float Ws[32][132];
  int t = threadIdx.x;
  int r0 = blockIdx.x * 64;
  int tx = t & 15;        // cols tx*8 .. tx*8+7 (of 128)
  int ty = t >> 4;        // rows ty*4 .. ty*4+3

  float acc[4][8];
#pragma unroll
  for (int i = 0; i < 4; ++i)
#pragma unroll
    for (int j = 0; j < 8; ++j) acc[i][j] = 0.f;

  int hrow = t >> 2;
  int hkk  = (t & 3) * 8;
  int wc   = t & 127;
  int wkk  = (t >> 7) * 16;
  const float* wbase = (wc < 64) ? (Wa + (size_t)wc * ldW)
                                 : (Wb + (size_t)(wc - 64) * ldW);

  for (int k0 = 0; k0 < K; k0 += 32) {
    float4 h0, h1;
    int gr = r0 + hrow;
    if (gr < N_NODES) {
      const float* p = H + (size_t)gr * ldH + k0 + hkk;
      h0 = *(const float4*)p;
      h1 = *(const float4*)(p + 4);
    } else {
      h0 = make_float4(0.f, 0.f, 0.f, 0.f);
      h1 = h0;
    }
    const float* wp = wbase + k0 + wkk;
    float4 w0 = *(const float4*)(wp + 0);
    float4 w1 = *(const float4*)(wp + 4);
    float4 w2 = *(const float4*)(wp + 8);
    float4 w3 = *(const float4*)(wp + 12);

    __syncthreads();
    Hs[hrow][hkk + 0] = h0.x; Hs[hrow][hkk + 1] = h0.y;
    Hs[hrow][hkk + 2] = h0.z; Hs[hrow][hkk + 3] = h0.w;
    Hs[hrow][hkk + 4] = h1.x; Hs[hrow][hkk + 5] = h1.y;
    Hs[hrow][hkk + 6] = h1.z; Hs[hrow][hkk + 7] = h1.w;
    Ws[wkk +  0][wc] = w0.x; Ws[wkk +  1][wc] = w0.y;
    Ws[wkk +  2][wc] = w0.z; Ws[wkk +  3][wc] = w0.w;
    Ws[wkk +  4][wc] = w1.x; Ws[wkk +  5][wc] = w1.y;
    Ws[wkk +  6][wc] = w1.z; Ws[wkk +  7][wc] = w1.w;
    Ws[wkk +  8][wc] = w2.x; Ws[wkk +  9][wc] = w2.y;
    Ws[wkk + 10][wc] = w2.z; Ws[wkk + 11][wc] = w2.w;
    Ws[wkk + 12][wc] = w3.x; Ws[wkk + 13][wc] = w3.y;
    Ws[wkk + 14][wc] = w3.z; Ws[wkk + 15][wc] = w3.w;
    __syncthreads();

#pragma unroll
    for (int k = 0; k < 32; ++k) {
      float a0 = Hs[ty * 4 + 0][k];
      float a1 = Hs[ty * 4 + 1][k];
      float a2 = Hs[ty * 4 + 2][k];
      float a3 = Hs[ty * 4 + 3][k];
      float4 b0 = *(const float4*)&Ws[k][tx * 8];
      float4 b1 = *(const float4*)&Ws[k][tx * 8 + 4];
      acc[0][0] += a0 * b0.x; acc[0][1] += a0 * b0.y; acc[0][2] += a0 * b0.z; acc[0][3] += a0 * b0.w;
      acc[0][4] += a0 * b1.x; acc[0][5] += a0 * b1.y; acc[0][6] += a0 * b1.z; acc[0][7] += a0 * b1.w;
      acc[1][0] += a1 * b0.x; acc[1][1] += a1 * b0.y; acc[1][2] += a1 * b0.z; acc[1][3] += a1 * b0.w;
      acc[1][4] += a1 * b1.x; acc[1][5] += a1 * b1.y; acc[1][6] += a1 * b1.z; acc[1][7] += a1 * b1.w;
      acc[2][0] += a2 * b0.x; acc[2][1] += a2 * b0.y; acc[2][2] += a2 * b0.z; acc[2][3] += a2 * b0.w;
      acc[2][4] += a2 * b1.x; acc[2][5] += a2 * b1.y; acc[2][6] += a2 * b1.z; acc[2][7] += a2 * b1.w;
      acc[3][0] += a3 * b0.x; acc[3][1] += a3 * b0.y; acc[3][2] += a3 * b0.z; acc[3][3] += a3 * b0.w;
      acc[3][4] += a3 * b1.x; acc[3][5] += a3 * b1.y; acc[3][6] += a3 * b1.z; acc[3][7] += a3 * b1.w;
    }
  }

  float b4a = 0.f, b4b = 0.f, b4c = 0.f, b4d = 0.f, b4e = 0.f, b4f = 0.f, b4g = 0.f, b4h = 0.f;
  if (tx >= 8) {
    int c = tx * 8 - 64;
    float4 ba = *(const float4*)&bias[c];
    float4 bb = *(const float4*)&bias[c + 4];
    b4a = ba.x; b4b = ba.y; b4c = ba.z; b4d = ba.w;
    b4e = bb.x; b4f = bb.y; b4g = bb.z; b4h = bb.w;
  }

#pragma unroll
  for (int i = 0; i < 4; ++i) {
    int row = r0 + ty * 4 + i;
    if (row >= N_NODES) continue;
    if (tx < 8) {
      unsigned int p0 = (unsigned int)f2bf(acc[i][0]) | ((unsigned int)f2bf(acc[i][1]) << 16);
      unsigned int p1 = (unsigned int)f2bf(acc[i][2]) | ((unsigned int)f2bf(acc[i][3]) << 16);
      unsigned int p2 = (unsigned int)f2bf(acc[i][4]) | ((unsigned int)f2bf(acc[i][5]) << 16);
      unsigned int p3 = (unsigned int)f2bf(acc[i][6]) | ((unsigned int)f2bf(acc[i][7]) << 16);
      uint4 pk = make_uint4(p0, p1, p2, p3);
      *(uint4*)&outA[(size_t)row * 64 + tx * 8] = pk;
    } else {
      int c = tx * 8 - 64;
      float* o = outB + (size_t)row * 64 + c;
      *(float4*)(o + 0) = make_float4(acc[i][0] + b4a, acc[i][1] + b4b, acc[i][2] + b4c, acc[i][3] + b4d);
      *(float4*)(o + 4) = make_float4(acc[i][4] + b4e, acc[i][5] + b4f, acc[i][6] + b4g, acc[i][7] + b4h);
    }
  }
}

// ---------------- aggregation (one wave per node, lane = feature) ----------------
// out[w] = relu(mean(y_nb[src]) + y_rt[w]) written to xcat column (ld 192)

__global__ __launch_bounds__(256)
void agg_fuse(const unsigned short* __restrict__ y_nb, const float* __restrict__ y_rt,
              const int* __restrict__ rowstart, const int* __restrict__ csr_src,
              float* __restrict__ out) {
  int w = (blockIdx.x * 256 + threadIdx.x) >> 6;
  int lane = threadIdx.x & 63;
  if (w >= N_NODES) return;
  int beg = rowstart[w], end = rowstart[w + 1];
  float s0 = 0.f, s1 = 0.f;
  int i = beg;
  for (; i + 8 <= end; i += 8) {
    int n0 = csr_src[i + 0], n1 = csr_src[i + 1], n2 = csr_src[i + 2], n3 = csr_src[i + 3];
    int n4 = csr_src[i + 4], n5 = csr_src[i + 5], n6 = csr_src[i + 6], n7 = csr_src[i + 7];
    float v0 = bf2f(y_nb[(size_t)n0 * 64 + lane]);
    float v1 = bf2f(y_nb[(size_t)n1 * 64 + lane]);
    float v2 = bf2f(y_nb[(size_t)n2 * 64 + lane]);
    float v3 = bf2f(y_nb[(size_t)n3 * 64 + lane]);
    float v4 = bf2f(y_nb[(size_t)n4 * 64 + lane]);
    float v5 = bf2f(y_nb[(size_t)n5 * 64 + lane]);
    float v6 = bf2f(y_nb[(size_t)n6 * 64 + lane]);
    float v7 = bf2f(y_nb[(size_t)n7 * 64 + lane]);
    s0 += (v0 + v1) + (v2 + v3);
    s1 += (v4 + v5) + (v6 + v7);
  }
  for (; i < end; ++i) s0 += bf2f(y_nb[(size_t)csr_src[i] * 64 + lane]);
  float s = s0 + s1;
  float deg = (float)(end - beg);
  float inv = 1.0f / fmaxf(deg, 1.0f);
  float h = s * inv + y_rt[(size_t)w * 64 + lane];
  out[(size_t)w * 192 + lane] = fmaxf(h, 0.f);
}

// ---------------- edge MLP, CSR order ----------------
// one wave per dst node; Q (incl. bm1) in registers; gather bf16 P rows;
// out[eid] = relu(P[src] + Q[dst]) . wm2 + bm2

__global__ __launch_bounds__(256)
void edge_mlp_csr(const int* __restrict__ rowstart, const int* __restrict__ csr_src,
                  const int* __restrict__ csr_eid,
                  const unsigned short* __restrict__ Pb, const float* __restrict__ Qf,
                  const float* __restrict__ wm2, const float* __restrict__ bm2v,
                  float* __restrict__ out) {
  int wv = (blockIdx.x * 256 + threadIdx.x) >> 6;
  if (wv >= N_NODES) return;
  int lane = threadIdx.x & 63;
  int grp = lane >> 4, l = lane & 15;
  int beg = rowstart[wv], end = rowstart[wv + 1];
  if (beg == end) return;
  float4 q = *(const float4*)&Qf[(size_t)wv * 64 + l * 4];
  float4 w = *(const float4*)&wm2[l * 4];
  float b2 = bm2v[0];
  for (int i = beg + grp; i < end; i += 4) {
    int s = csr_src[i];
    int eid = csr_eid[i];
    uint2 pu = *(const uint2*)&Pb[(size_t)s * 64 + l * 4];
    float p0 = bfraw(pu.x << 16);
    float p1 = bfraw(pu.x & 0xFFFF0000u);
    float p2 = bfraw(pu.y << 16);
    float p3 = bfraw(pu.y & 0xFFFF0000u);
    float h0 = fmaxf(p0 + q.x, 0.f);
    float h1 = fmaxf(p1 + q.y, 0.f);
    float h2 = fmaxf(p2 + q.z, 0.f);
    float h3 = fmaxf(p3 + q.w, 0.f);
    float part = h0 * w.x + h1 * w.y + h2 * w.z + h3 * w.w;
    part += __shfl_xor(part, 1);
    part += __shfl_xor(part, 2);
    part += __shfl_xor(part, 4);
    part += __shfl_xor(part, 8);
    if (l == 0) out[eid] = part + b2;
  }
}

// ---------------- launch ----------------

extern "C" void kernel_launch(void* const* d_in, const int* in_sizes, int n_in,
                              void* d_out, int out_size, void* d_ws, size_t ws_size,
                              hipStream_t stream) {
  (void)in_sizes; (void)n_in; (void)out_size; (void)ws_size;
  const float* x   = (const float*)d_in[0];
  const int*   src = (const int*)d_in[1];
  const int*   dst = (const int*)d_in[2];
  const float* Wl0 = (const float*)d_in[3];
  const float* bl0 = (const float*)d_in[4];
  const float* Wr0 = (const float*)d_in[5];
  const float* Wl1 = (const float*)d_in[6];
  const float* bl1 = (const float*)d_in[7];
  const float* Wr1 = (const float*)d_in[8];
  const float* Wl2 = (const float*)d_in[9];
  const float* bl2 = (const float*)d_in[10];
  const float* Wr2 = (const float*)d_in[11];
  const float* Wm1 = (const float*)d_in[12];
  const float* bm1 = (const float*)d_in[13];
  const float* Wm2 = (const float*)d_in[14];
  const float* bm2 = (const float*)d_in[15];
  float* out = (float*)d_out;

  char* ws = (char*)d_ws;
  size_t off = 0;
  auto take = [&](size_t bytes) {
    char* p = ws + off;
    off = (off + bytes + 255) & ~(size_t)255;
    return p;
  };
  int*   deg      = (int*)take((size_t)2 * N_NODES * 4);   // deg | cursor adjacent
  int*   cursor   = deg + N_NODES;
  int*   rowstart = (int*)take((size_t)(N_NODES + 1) * 4);
  int*   bsum     = (int*)take((size_t)SCAN_BLOCKS * 4);
  int*   boff     = (int*)take((size_t)SCAN_BLOCKS * 4);
  int*   csr_src  = (int*)take((size_t)N_EDGES * 4);
  int*   csr_eid  = (int*)take((size_t)N_EDGES * 4);
  float* xcat     = (float*)take((size_t)N_NODES * 192 * 4);
  unsigned short* y_nb = (unsigned short*)take((size_t)N_NODES * 64 * 2);  // also P
  float* y_rt     = (float*)take((size_t)N_NODES * 64 * 4);                 // also Q

  hipMemsetAsync(deg, 0, (size_t)2 * N_NODES * 4, stream);

  count_deg<<<(N_EDGES + 255) / 256, 256, 0, stream>>>(dst, deg);
  k_blocksum<<<SCAN_BLOCKS, 256, 0, stream>>>(deg, bsum);
  k_scanb<<<1, 256, 0, stream>>>(bsum, boff, rowstart);
  k_local<<<SCAN_BLOCKS, 256, 0, stream>>>(deg, boff, rowstart);
  scatter_edges<<<(N_EDGES + 255) / 256, 256, 0, stream>>>(src, dst, rowstart, cursor,
                                                           csr_src, csr_eid);

  int gemm_grid = (N_NODES + 63) / 64;
  int node_waves_grid = (N_NODES * 64) / 256;  // 12500
  // layer 0
  gemm_dual<<<gemm_grid, 256, 0, stream>>>(x, IN_CH, IN_CH, Wl0, Wr0, IN_CH, bl0, y_nb, y_rt);
  agg_fuse<<<node_waves_grid, 256, 0, stream>>>(y_nb, y_rt, rowstart, csr_src, xcat + 0);
  // layer 1
  gemm_dual<<<gemm_grid, 256, 0, stream>>>(xcat + 0, 192, HID, Wl1, Wr1, HID, bl1, y_nb, y_rt);
  agg_fuse<<<node_waves_grid, 256, 0, stream>>>(y_nb, y_rt, rowstart, csr_src, xcat + 64);
  // layer 2
  gemm_dual<<<gemm_grid, 256, 0, stream>>>(xcat + 64, 192, HID, Wl2, Wr2, HID, bl2, y_nb, y_rt);
  agg_fuse<<<node_waves_grid, 256, 0, stream>>>(y_nb, y_rt, rowstart, csr_src, xcat + 128);
  // P (bf16) | Q+bm1 (fp32)
  gemm_dual<<<gemm_grid, 256, 0, stream>>>(xcat, 192, 192, Wm1, Wm1 + 192, 384, bm1, y_nb, y_rt);
  edge_mlp_csr<<<node_waves_grid, 256, 0, stream>>>(rowstart, csr_src, csr_eid,
                                                    y_nb, y_rt, Wm2, bm2, out);
}

// Round 4
// 383.404 us; speedup vs baseline: 1.0988x; 1.0348x over previous
//
#include <hip/hip_runtime.h>

#define N_NODES 50000
#define N_EDGES 800000
#define IN_CH   128
#define HID     64
#define SCAN_BLOCKS ((N_NODES + 255) / 256)   // 196

// ---------------- bf16 helpers ----------------

__device__ inline float bfraw(unsigned int bits) {
  float f; __builtin_memcpy(&f, &bits, 4); return f;
}
__device__ inline float bf2f(unsigned short u) {
  return bfraw(((unsigned int)u) << 16);
}
__device__ inline unsigned short f2bf(float f) {
  unsigned int x; __builtin_memcpy(&x, &f, 4);
  return (unsigned short)((x + 0x7FFFu + ((x >> 16) & 1u)) >> 16);
}

// ---------------- CSR build ----------------

__global__ __launch_bounds__(256) void count_deg(const int* __restrict__ dst,
                                                 int* __restrict__ deg) {
  int e = blockIdx.x * 256 + threadIdx.x;
  if (e < N_EDGES) atomicAdd(&deg[dst[e]], 1);
}

__global__ __launch_bounds__(256) void k_blocksum(const int* __restrict__ deg,
                                                  int* __restrict__ bsum) {
  int t = threadIdx.x, lane = t & 63, wid = t >> 6;
  int i = blockIdx.x * 256 + t;
  int v = (i < N_NODES) ? deg[i] : 0;
#pragma unroll
  for (int d = 32; d > 0; d >>= 1) v += __shfl_down(v, d);
  __shared__ int ws[4];
  if (lane == 0) ws[wid] = v;
  __syncthreads();
  if (t == 0) bsum[blockIdx.x] = ws[0] + ws[1] + ws[2] + ws[3];
}

__global__ __launch_bounds__(256) void k_scanb(const int* __restrict__ bsum,
                                               int* __restrict__ boff,
                                               int* __restrict__ rowstart) {
  int t = threadIdx.x, lane = t & 63, wid = t >> 6;
  int v = (t < SCAN_BLOCKS) ? bsum[t] : 0;
  int orig = v;
#pragma unroll
  for (int d = 1; d < 64; d <<= 1) {
    int u = __shfl_up(v, d);
    if (lane >= d) v += u;
  }
  __shared__ int ws[4];
  if (lane == 63) ws[wid] = v;
  __syncthreads();
  int off = 0;
  for (int j = 0; j < wid; ++j) off += ws[j];
  if (t < SCAN_BLOCKS) boff[t] = v - orig + off;
  if (t == 0) rowstart[N_NODES] = N_EDGES;
}

// per-block exclusive scan + block offset -> rowstart
__global__ __launch_bounds__(256) void k_local(const int* __restrict__ deg,
                                               const int* __restrict__ boff,
                                               int* __restrict__ rowstart) {
  int t = threadIdx.x, lane = t & 63, wid = t >> 6;
  int i = blockIdx.x * 256 + t;
  int orig = (i < N_NODES) ? deg[i] : 0;
  int v = orig;
#pragma unroll
  for (int d = 1; d < 64; d <<= 1) {
    int u = __shfl_up(v, d);
    if (lane >= d) v += u;
  }
  __shared__ int ws[4];
  if (lane == 63) ws[wid] = v;
  __syncthreads();
  int off = boff[blockIdx.x];
  for (int j = 0; j < wid; ++j) off += ws[j];
  if (i < N_NODES) rowstart[i] = v - orig + off;
}

// one random 8B store per edge: (src, eid) packed
__global__ __launch_bounds__(256) void scatter_edges(const int* __restrict__ src,
                                                     const int* __restrict__ dst,
                                                     const int* __restrict__ rowstart,
                                                     int* __restrict__ cursor,
                                                     int2* __restrict__ csr_pack) {
  int e = blockIdx.x * 256 + threadIdx.x;
  if (e < N_EDGES) {
    int d = dst[e];
    int pos = atomicAdd(&cursor[d], 1);
    csr_pack[rowstart[d] + pos] = make_int2(src[e], e);
  }
}

// ---------------- dual GEMM ----------------
// outA[N,64] (bf16) = H @ Wa^T          (gathered later)
// outB[N,64] (fp32) = H @ Wb^T + bias   (streamed later)

__global__ __launch_bounds__(256)
void gemm_dual(const float* __restrict__ H, int ldH, int K,
               const float* __restrict__ Wa, const float* __restrict__ Wb, int ldW,
               const float* __restrict__ bias,
               unsigned short* __restrict__ outA, float* __restrict__ outB) {
  __shared__ float Hs[64][33];
  __shared__ float Ws[32][132];
  int t = threadIdx.x;
  int r0 = blockIdx.x * 64;
  int tx = t & 15;
  int ty = t >> 4;

  float acc[4][8];
#pragma unroll
  for (int i = 0; i < 4; ++i)
#pragma unroll
    for (int j = 0; j < 8; ++j) acc[i][j] = 0.f;

  int hrow = t >> 2;
  int hkk  = (t & 3) * 8;
  int wc   = t & 127;
  int wkk  = (t >> 7) * 16;
  const float* wbase = (wc < 64) ? (Wa + (size_t)wc * ldW)
                                 : (Wb + (size_t)(wc - 64) * ldW);

  for (int k0 = 0; k0 < K; k0 += 32) {
    float4 h0, h1;
    int gr = r0 + hrow;
    if (gr < N_NODES) {
      const float* p = H + (size_t)gr * ldH + k0 + hkk;
      h0 = *(const float4*)p;
      h1 = *(const float4*)(p + 4);
    } else {
      h0 = make_float4(0.f, 0.f, 0.f, 0.f);
      h1 = h0;
    }
    const float* wp = wbase + k0 + wkk;
    float4 w0 = *(const float4*)(wp + 0);
    float4 w1 = *(const float4*)(wp + 4);
    float4 w2 = *(const float4*)(wp + 8);
    float4 w3 = *(const float4*)(wp + 12);

    __syncthreads();
    Hs[hrow][hkk + 0] = h0.x; Hs[hrow][hkk + 1] = h0.y;
    Hs[hrow][hkk + 2] = h0.z; Hs[hrow][hkk + 3] = h0.w;
    Hs[hrow][hkk + 4] = h1.x; Hs[hrow][hkk + 5] = h1.y;
    Hs[hrow][hkk + 6] = h1.z; Hs[hrow][hkk + 7] = h1.w;
    Ws[wkk +  0][wc] = w0.x; Ws[wkk +  1][wc] = w0.y;
    Ws[wkk +  2][wc] = w0.z; Ws[wkk +  3][wc] = w0.w;
    Ws[wkk +  4][wc] = w1.x; Ws[wkk +  5][wc] = w1.y;
    Ws[wkk +  6][wc] = w1.z; Ws[wkk +  7][wc] = w1.w;
    Ws[wkk +  8][wc] = w2.x; Ws[wkk +  9][wc] = w2.y;
    Ws[wkk + 10][wc] = w2.z; Ws[wkk + 11][wc] = w2.w;
    Ws[wkk + 12][wc] = w3.x; Ws[wkk + 13][wc] = w3.y;
    Ws[wkk + 14][wc] = w3.z; Ws[wkk + 15][wc] = w3.w;
    __syncthreads();

#pragma unroll
    for (int k = 0; k < 32; ++k) {
      float a0 = Hs[ty * 4 + 0][k];
      float a1 = Hs[ty * 4 + 1][k];
      float a2 = Hs[ty * 4 + 2][k];
      float a3 = Hs[ty * 4 + 3][k];
      float4 b0 = *(const float4*)&Ws[k][tx * 8];
      float4 b1 = *(const float4*)&Ws[k][tx * 8 + 4];
      acc[0][0] += a0 * b0.x; acc[0][1] += a0 * b0.y; acc[0][2] += a0 * b0.z; acc[0][3] += a0 * b0.w;
      acc[0][4] += a0 * b1.x; acc[0][5] += a0 * b1.y; acc[0][6] += a0 * b1.z; acc[0][7] += a0 * b1.w;
      acc[1][0] += a1 * b0.x; acc[1][1] += a1 * b0.y; acc[1][2] += a1 * b0.z; acc[1][3] += a1 * b0.w;
      acc[1][4] += a1 * b1.x; acc[1][5] += a1 * b1.y; acc[1][6] += a1 * b1.z; acc[1][7] += a1 * b1.w;
      acc[2][0] += a2 * b0.x; acc[2][1] += a2 * b0.y; acc[2][2] += a2 * b0.z; acc[2][3] += a2 * b0.w;
      acc[2][4] += a2 * b1.x; acc[2][5] += a2 * b1.y; acc[2][6] += a2 * b1.z; acc[2][7] += a2 * b1.w;
      acc[3][0] += a3 * b0.x; acc[3][1] += a3 * b0.y; acc[3][2] += a3 * b0.z; acc[3][3] += a3 * b0.w;
      acc[3][4] += a3 * b1.x; acc[3][5] += a3 * b1.y; acc[3][6] += a3 * b1.z; acc[3][7] += a3 * b1.w;
    }
  }

  float b4a = 0.f, b4b = 0.f, b4c = 0.f, b4d = 0.f, b4e = 0.f, b4f = 0.f, b4g = 0.f, b4h = 0.f;
  if (tx >= 8) {
    int c = tx * 8 - 64;
    float4 ba = *(const float4*)&bias[c];
    float4 bb = *(const float4*)&bias[c + 4];
    b4a = ba.x; b4b = ba.y; b4c = ba.z; b4d = ba.w;
    b4e = bb.x; b4f = bb.y; b4g = bb.z; b4h = bb.w;
  }

#pragma unroll
  for (int i = 0; i < 4; ++i) {
    int row = r0 + ty * 4 + i;
    if (row >= N_NODES) continue;
    if (tx < 8) {
      unsigned int p0 = (unsigned int)f2bf(acc[i][0]) | ((unsigned int)f2bf(acc[i][1]) << 16);
      unsigned int p1 = (unsigned int)f2bf(acc[i][2]) | ((unsigned int)f2bf(acc[i][3]) << 16);
      unsigned int p2 = (unsigned int)f2bf(acc[i][4]) | ((unsigned int)f2bf(acc[i][5]) << 16);
      unsigned int p3 = (unsigned int)f2bf(acc[i][6]) | ((unsigned int)f2bf(acc[i][7]) << 16);
      uint4 pk = make_uint4(p0, p1, p2, p3);
      *(uint4*)&outA[(size_t)row * 64 + tx * 8] = pk;
    } else {
      int c = tx * 8 - 64;
      float* o = outB + (size_t)row * 64 + c;
      *(float4*)(o + 0) = make_float4(acc[i][0] + b4a, acc[i][1] + b4b, acc[i][2] + b4c, acc[i][3] + b4d);
      *(float4*)(o + 4) = make_float4(acc[i][4] + b4e, acc[i][5] + b4f, acc[i][6] + b4g, acc[i][7] + b4h);
    }
  }
}

// ---------------- aggregation (one wave per node, lane = feature) ----------------

__global__ __launch_bounds__(256)
void agg_fuse(const unsigned short* __restrict__ y_nb, const float* __restrict__ y_rt,
              const int* __restrict__ rowstart, const int2* __restrict__ csr_pack,
              float* __restrict__ out) {
  int w = (blockIdx.x * 256 + threadIdx.x) >> 6;
  int lane = threadIdx.x & 63;
  if (w >= N_NODES) return;
  int beg = rowstart[w], end = rowstart[w + 1];
  float s0 = 0.f, s1 = 0.f;
  int i = beg;
  for (; i + 8 <= end; i += 8) {
    int n0 = csr_pack[i + 0].x, n1 = csr_pack[i + 1].x, n2 = csr_pack[i + 2].x, n3 = csr_pack[i + 3].x;
    int n4 = csr_pack[i + 4].x, n5 = csr_pack[i + 5].x, n6 = csr_pack[i + 6].x, n7 = csr_pack[i + 7].x;
    float v0 = bf2f(y_nb[(size_t)n0 * 64 + lane]);
    float v1 = bf2f(y_nb[(size_t)n1 * 64 + lane]);
    float v2 = bf2f(y_nb[(size_t)n2 * 64 + lane]);
    float v3 = bf2f(y_nb[(size_t)n3 * 64 + lane]);
    float v4 = bf2f(y_nb[(size_t)n4 * 64 + lane]);
    float v5 = bf2f(y_nb[(size_t)n5 * 64 + lane]);
    float v6 = bf2f(y_nb[(size_t)n6 * 64 + lane]);
    float v7 = bf2f(y_nb[(size_t)n7 * 64 + lane]);
    s0 += (v0 + v1) + (v2 + v3);
    s1 += (v4 + v5) + (v6 + v7);
  }
  for (; i < end; ++i) s0 += bf2f(y_nb[(size_t)csr_pack[i].x * 64 + lane]);
  float s = s0 + s1;
  float deg = (float)(end - beg);
  float inv = 1.0f / fmaxf(deg, 1.0f);
  float h = s * inv + y_rt[(size_t)w * 64 + lane];
  out[(size_t)w * 192 + lane] = fmaxf(h, 0.f);
}

// ---------------- edge MLP, CSR order ----------------
// one wave per dst node; Q (incl. bm1) in registers; gather bf16 P rows;
// out[eid] = relu(P[src] + Q[dst]) . wm2 + bm2

__global__ __launch_bounds__(256)
void edge_mlp_csr(const int* __restrict__ rowstart, const int2* __restrict__ csr_pack,
                  const unsigned short* __restrict__ Pb, const float* __restrict__ Qf,
                  const float* __restrict__ wm2, const float* __restrict__ bm2v,
                  float* __restrict__ out) {
  int wv = (blockIdx.x * 256 + threadIdx.x) >> 6;
  if (wv >= N_NODES) return;
  int lane = threadIdx.x & 63;
  int grp = lane >> 4, l = lane & 15;
  int beg = rowstart[wv], end = rowstart[wv + 1];
  if (beg == end) return;
  float4 q = *(const float4*)&Qf[(size_t)wv * 64 + l * 4];
  float4 w = *(const float4*)&wm2[l * 4];
  float b2 = bm2v[0];
  for (int i = beg + grp; i < end; i += 4) {
    int2 pk = csr_pack[i];
    int s = pk.x;
    int eid = pk.y;
    uint2 pu = *(const uint2*)&Pb[(size_t)s * 64 + l * 4];
    float p0 = bfraw(pu.x << 16);
    float p1 = bfraw(pu.x & 0xFFFF0000u);
    float p2 = bfraw(pu.y << 16);
    float p3 = bfraw(pu.y & 0xFFFF0000u);
    float h0 = fmaxf(p0 + q.x, 0.f);
    float h1 = fmaxf(p1 + q.y, 0.f);
    float h2 = fmaxf(p2 + q.z, 0.f);
    float h3 = fmaxf(p3 + q.w, 0.f);
    float part = h0 * w.x + h1 * w.y + h2 * w.z + h3 * w.w;
    part += __shfl_xor(part, 1);
    part += __shfl_xor(part, 2);
    part += __shfl_xor(part, 4);
    part += __shfl_xor(part, 8);
    if (l == 0) out[eid] = part + b2;
  }
}

// ---------------- launch ----------------

extern "C" void kernel_launch(void* const* d_in, const int* in_sizes, int n_in,
                              void* d_out, int out_size, void* d_ws, size_t ws_size,
                              hipStream_t stream) {
  (void)in_sizes; (void)n_in; (void)out_size; (void)ws_size;
  const float* x   = (const float*)d_in[0];
  const int*   src = (const int*)d_in[1];
  const int*   dst = (const int*)d_in[2];
  const float* Wl0 = (const float*)d_in[3];
  const float* bl0 = (const float*)d_in[4];
  const float* Wr0 = (const float*)d_in[5];
  const float* Wl1 = (const float*)d_in[6];
  const float* bl1 = (const float*)d_in[7];
  const float* Wr1 = (const float*)d_in[8];
  const float* Wl2 = (const float*)d_in[9];
  const float* bl2 = (const float*)d_in[10];
  const float* Wr2 = (const float*)d_in[11];
  const float* Wm1 = (const float*)d_in[12];
  const float* bm1 = (const float*)d_in[13];
  const float* Wm2 = (const float*)d_in[14];
  const float* bm2 = (const float*)d_in[15];
  float* out = (float*)d_out;

  char* ws = (char*)d_ws;
  size_t off = 0;
  auto take = [&](size_t bytes) {
    char* p = ws + off;
    off = (off + bytes + 255) & ~(size_t)255;
    return p;
  };
  int*   deg      = (int*)take((size_t)2 * N_NODES * 4);   // deg | cursor adjacent
  int*   cursor   = deg + N_NODES;
  int*   rowstart = (int*)take((size_t)(N_NODES + 1) * 4);
  int*   bsum     = (int*)take((size_t)SCAN_BLOCKS * 4);
  int*   boff     = (int*)take((size_t)SCAN_BLOCKS * 4);
  int2*  csr_pack = (int2*)take((size_t)N_EDGES * 8);
  float* xcat     = (float*)take((size_t)N_NODES * 192 * 4);
  unsigned short* y_nb = (unsigned short*)take((size_t)N_NODES * 64 * 2);  // also P
  float* y_rt     = (float*)take((size_t)N_NODES * 64 * 4);                 // also Q

  hipMemsetAsync(deg, 0, (size_t)2 * N_NODES * 4, stream);

  count_deg<<<(N_EDGES + 255) / 256, 256, 0, stream>>>(dst, deg);
  k_blocksum<<<SCAN_BLOCKS, 256, 0, stream>>>(deg, bsum);
  k_scanb<<<1, 256, 0, stream>>>(bsum, boff, rowstart);
  k_local<<<SCAN_BLOCKS, 256, 0, stream>>>(deg, boff, rowstart);
  scatter_edges<<<(N_EDGES + 255) / 256, 256, 0, stream>>>(src, dst, rowstart, cursor, csr_pack);

  int gemm_grid = (N_NODES + 63) / 64;
  int node_waves_grid = (N_NODES * 64) / 256;  // 12500
  // layer 0
  gemm_dual<<<gemm_grid, 256, 0, stream>>>(x, IN_CH, IN_CH, Wl0, Wr0, IN_CH, bl0, y_nb, y_rt);
  agg_fuse<<<node_waves_grid, 256, 0, stream>>>(y_nb, y_rt, rowstart, csr_pack, xcat + 0);
  // layer 1
  gemm_dual<<<gemm_grid, 256, 0, stream>>>(xcat + 0, 192, HID, Wl1, Wr1, HID, bl1, y_nb, y_rt);
  agg_fuse<<<node_waves_grid, 256, 0, stream>>>(y_nb, y_rt, rowstart, csr_pack, xcat + 64);
  // layer 2
  gemm_dual<<<gemm_grid, 256, 0, stream>>>(xcat + 64, 192, HID, Wl2, Wr2, HID, bl2, y_nb, y_rt);
  agg_fuse<<<node_waves_grid, 256, 0, stream>>>(y_nb, y_rt, rowstart, csr_pack, xcat + 128);
  // P (bf16) | Q+bm1 (fp32)
  gemm_dual<<<gemm_grid, 256, 0, stream>>>(xcat, 192, 192, Wm1, Wm1 + 192, 384, bm1, y_nb, y_rt);
  edge_mlp_csr<<<node_waves_grid, 256, 0, stream>>>(rowstart, csr_pack, y_nb, y_rt, Wm2, bm2, out);
}

// Round 5
// 367.055 us; speedup vs baseline: 1.1477x; 1.0445x over previous
//
#include <hip/hip_runtime.h>

#define N_NODES 50000
#define N_EDGES 800000
#define IN_CH   128
#define HID     64
#define SCAN_BLOCKS ((N_NODES + 255) / 256)   // 196

typedef __attribute__((ext_vector_type(8))) short bf16x8;
typedef __attribute__((ext_vector_type(4))) float f32x4;

// ---------------- bf16 helpers ----------------

__device__ inline float bfraw(unsigned int bits) {
  float f; __builtin_memcpy(&f, &bits, 4); return f;
}
__device__ inline float bf2f(unsigned short u) {
  return bfraw(((unsigned int)u) << 16);
}
__device__ inline unsigned short f2bf(float f) {
  unsigned int x; __builtin_memcpy(&x, &f, 4);
  return (unsigned short)((x + 0x7FFFu + ((x >> 16) & 1u)) >> 16);
}

// ---------------- CSR build ----------------

__global__ __launch_bounds__(256) void count_deg(const int* __restrict__ dst,
                                                 int* __restrict__ deg) {
  int e = blockIdx.x * 256 + threadIdx.x;
  if (e < N_EDGES) atomicAdd(&deg[dst[e]], 1);
}

__global__ __launch_bounds__(256) void k_blocksum(const int* __restrict__ deg,
                                                  int* __restrict__ bsum) {
  int t = threadIdx.x, lane = t & 63, wid = t >> 6;
  int i = blockIdx.x * 256 + t;
  int v = (i < N_NODES) ? deg[i] : 0;
#pragma unroll
  for (int d = 32; d > 0; d >>= 1) v += __shfl_down(v, d);
  __shared__ int ws[4];
  if (lane == 0) ws[wid] = v;
  __syncthreads();
  if (t == 0) bsum[blockIdx.x] = ws[0] + ws[1] + ws[2] + ws[3];
}

__global__ __launch_bounds__(256) void k_scanb(const int* __restrict__ bsum,
                                               int* __restrict__ boff,
                                               int* __restrict__ rowstart) {
  int t = threadIdx.x, lane = t & 63, wid = t >> 6;
  int v = (t < SCAN_BLOCKS) ? bsum[t] : 0;
  int orig = v;
#pragma unroll
  for (int d = 1; d < 64; d <<= 1) {
    int u = __shfl_up(v, d);
    if (lane >= d) v += u;
  }
  __shared__ int ws[4];
  if (lane == 63) ws[wid] = v;
  __syncthreads();
  int off = 0;
  for (int j = 0; j < wid; ++j) off += ws[j];
  if (t < SCAN_BLOCKS) boff[t] = v - orig + off;
  if (t == 0) rowstart[N_NODES] = N_EDGES;
}

__global__ __launch_bounds__(256) void k_local(const int* __restrict__ deg,
                                               const int* __restrict__ boff,
                                               int* __restrict__ rowstart) {
  int t = threadIdx.x, lane = t & 63, wid = t >> 6;
  int i = blockIdx.x * 256 + t;
  int orig = (i < N_NODES) ? deg[i] : 0;
  int v = orig;
#pragma unroll
  for (int d = 1; d < 64; d <<= 1) {
    int u = __shfl_up(v, d);
    if (lane >= d) v += u;
  }
  __shared__ int ws[4];
  if (lane == 63) ws[wid] = v;
  __syncthreads();
  int off = boff[blockIdx.x];
  for (int j = 0; j < wid; ++j) off += ws[j];
  if (i < N_NODES) rowstart[i] = v - orig + off;
}

// one random 8B store per edge: (src, eid) packed
__global__ __launch_bounds__(256) void scatter_edges(const int* __restrict__ src,
                                                     const int* __restrict__ dst,
                                                     const int* __restrict__ rowstart,
                                                     int* __restrict__ cursor,
                                                     int2* __restrict__ csr_pack) {
  int e = blockIdx.x * 256 + threadIdx.x;
  if (e < N_EDGES) {
    int d = dst[e];
    int pos = atomicAdd(&cursor[d], 1);
    csr_pack[rowstart[d] + pos] = make_int2(src[e], e);
  }
}

// ---------------- fp32 -> bf16 hi/lo split ----------------

// x [N,128] -> xh/xl [N,128]; each thread does 8 elements
__global__ __launch_bounds__(256) void conv_x(const float* __restrict__ x,
                                              unsigned short* __restrict__ xh,
                                              unsigned short* __restrict__ xl) {
  size_t base = ((size_t)blockIdx.x * 256 + threadIdx.x) * 8;
  float4 a = *(const float4*)&x[base];
  float4 b = *(const float4*)&x[base + 4];
  float v[8] = {a.x, a.y, a.z, a.w, b.x, b.y, b.z, b.w};
  unsigned short h[8], l[8];
#pragma unroll
  for (int j = 0; j < 8; ++j) {
    h[j] = f2bf(v[j]);
    l[j] = f2bf(v[j] - bf2f(h[j]));
  }
  uint4 uh = make_uint4((unsigned)h[0] | ((unsigned)h[1] << 16),
                        (unsigned)h[2] | ((unsigned)h[3] << 16),
                        (unsigned)h[4] | ((unsigned)h[5] << 16),
                        (unsigned)h[6] | ((unsigned)h[7] << 16));
  uint4 ul = make_uint4((unsigned)l[0] | ((unsigned)l[1] << 16),
                        (unsigned)l[2] | ((unsigned)l[3] << 16),
                        (unsigned)l[4] | ((unsigned)l[5] << 16),
                        (unsigned)l[6] | ((unsigned)l[7] << 16));
  *(uint4*)&xh[base] = uh;
  *(uint4*)&xl[base] = ul;
}

// Wa[64][K] (ld ldW), Wb[64][K] (ld ldW) -> Bh/Bl [128][K] contiguous
__global__ __launch_bounds__(256) void convW(const float* __restrict__ Wa,
                                             const float* __restrict__ Wb, int ldW, int K,
                                             unsigned short* __restrict__ Bh,
                                             unsigned short* __restrict__ Bl) {
  int r = blockIdx.x;       // 0..127
  int k = threadIdx.x;      // 0..K-1 (blockDim == K)
  const float* wsrc = (r < 64) ? (Wa + (size_t)r * ldW) : (Wb + (size_t)(r - 64) * ldW);
  float v = wsrc[k];
  unsigned short hi = f2bf(v);
  Bh[(size_t)r * K + k] = hi;
  Bl[(size_t)r * K + k] = f2bf(v - bf2f(hi));
}

// ---------------- MFMA dual GEMM ----------------
// out cols 0..63  -> outA bf16 (= H @ Wa^T), cols 64..127 -> outB fp32 (= H @ Wb^T + bias)
// A given as hi/lo bf16 [N rows, ldA]; B as hi/lo bf16 [128, K].
// Compensated: acc += Ah*Bh + Al*Bh + Ah*Bl  (error ~2^-16 relative).
// Fragments: A row = lane&15, B col = lane&15, k = k0 + (lane>>4)*8 + j (same map
// for A and B, so any k-permutation inside the instruction cancels).
// C/D: col = lane&15, row = (lane>>4)*4 + reg   [m89-verified].

__global__ __launch_bounds__(256)
void gemm_mfma(const unsigned short* __restrict__ Ah, const unsigned short* __restrict__ Al,
               int ldA, int K,
               const unsigned short* __restrict__ Bh, const unsigned short* __restrict__ Bl,
               const float* __restrict__ bias,
               unsigned short* __restrict__ outA, float* __restrict__ outB) {
  int t = threadIdx.x;
  int lane = t & 63, wave = t >> 6;
  int r0 = blockIdx.x * 64;
  int col0 = wave * 32;             // this wave's first output col
  int lrow = lane & 15;
  int kgrp = (lane >> 4) * 8;

  f32x4 z = {0.f, 0.f, 0.f, 0.f};
  f32x4 acc[4][2];
#pragma unroll
  for (int rt = 0; rt < 4; ++rt)
#pragma unroll
    for (int ct = 0; ct < 2; ++ct) acc[rt][ct] = z;

  int arow[4];
#pragma unroll
  for (int rt = 0; rt < 4; ++rt) {
    int r = r0 + rt * 16 + lrow;
    arow[rt] = (r < N_NODES) ? r : (N_NODES - 1);
  }
  int bcol0 = col0 + lrow;

  for (int k0 = 0; k0 < K; k0 += 32) {
    bf16x8 ah[4], al[4], bh[2], bl[2];
#pragma unroll
    for (int rt = 0; rt < 4; ++rt) {
      size_t o = (size_t)arow[rt] * ldA + k0 + kgrp;
      ah[rt] = *(const bf16x8*)(Ah + o);
      al[rt] = *(const bf16x8*)(Al + o);
    }
#pragma unroll
    for (int ct = 0; ct < 2; ++ct) {
      size_t o = (size_t)(bcol0 + ct * 16) * K + k0 + kgrp;
      bh[ct] = *(const bf16x8*)(Bh + o);
      bl[ct] = *(const bf16x8*)(Bl + o);
    }
#pragma unroll
    for (int rt = 0; rt < 4; ++rt)
#pragma unroll
      for (int ct = 0; ct < 2; ++ct) {
        acc[rt][ct] = __builtin_amdgcn_mfma_f32_16x16x32_bf16(ah[rt], bh[ct], acc[rt][ct], 0, 0, 0);
        acc[rt][ct] = __builtin_amdgcn_mfma_f32_16x16x32_bf16(al[rt], bh[ct], acc[rt][ct], 0, 0, 0);
        acc[rt][ct] = __builtin_amdgcn_mfma_f32_16x16x32_bf16(ah[rt], bl[ct], acc[rt][ct], 0, 0, 0);
      }
  }

  int crow = (lane >> 4) * 4;
#pragma unroll
  for (int ct = 0; ct < 2; ++ct) {
    int col = col0 + ct * 16 + lrow;
    bool isA = (col < 64);          // wave-uniform
    float bv = 0.f;
    if (!isA) bv = bias[col - 64];
#pragma unroll
    for (int rt = 0; rt < 4; ++rt) {
#pragma unroll
      for (int reg = 0; reg < 4; ++reg) {
        int row = r0 + rt * 16 + crow + reg;
        if (row < N_NODES) {
          float v = acc[rt][ct][reg];
          if (isA) outA[(size_t)row * 64 + col] = f2bf(v);
          else     outB[(size_t)row * 64 + (col - 64)] = v + bv;
        }
      }
    }
  }
}

// ---------------- aggregation (one wave per node, lane = feature) ----------------
// writes hi/lo bf16 into the concatenated node-embedding arrays (ld 192)

__global__ __launch_bounds__(256)
void agg_fuse(const unsigned short* __restrict__ y_nb, const float* __restrict__ y_rt,
              const int* __restrict__ rowstart, const int2* __restrict__ csr_pack,
              unsigned short* __restrict__ oh, unsigned short* __restrict__ ol) {
  int w = (blockIdx.x * 256 + threadIdx.x) >> 6;
  int lane = threadIdx.x & 63;
  if (w >= N_NODES) return;
  int beg = rowstart[w], end = rowstart[w + 1];
  float s0 = 0.f, s1 = 0.f;
  int i = beg;
  for (; i + 8 <= end; i += 8) {
    int n0 = csr_pack[i + 0].x, n1 = csr_pack[i + 1].x, n2 = csr_pack[i + 2].x, n3 = csr_pack[i + 3].x;
    int n4 = csr_pack[i + 4].x, n5 = csr_pack[i + 5].x, n6 = csr_pack[i + 6].x, n7 = csr_pack[i + 7].x;
    float v0 = bf2f(y_nb[(size_t)n0 * 64 + lane]);
    float v1 = bf2f(y_nb[(size_t)n1 * 64 + lane]);
    float v2 = bf2f(y_nb[(size_t)n2 * 64 + lane]);
    float v3 = bf2f(y_nb[(size_t)n3 * 64 + lane]);
    float v4 = bf2f(y_nb[(size_t)n4 * 64 + lane]);
    float v5 = bf2f(y_nb[(size_t)n5 * 64 + lane]);
    float v6 = bf2f(y_nb[(size_t)n6 * 64 + lane]);
    float v7 = bf2f(y_nb[(size_t)n7 * 64 + lane]);
    s0 += (v0 + v1) + (v2 + v3);
    s1 += (v4 + v5) + (v6 + v7);
  }
  for (; i < end; ++i) s0 += bf2f(y_nb[(size_t)csr_pack[i].x * 64 + lane]);
  float s = s0 + s1;
  float deg = (float)(end - beg);
  float inv = 1.0f / fmaxf(deg, 1.0f);
  float h = s * inv + y_rt[(size_t)w * 64 + lane];
  float hr = fmaxf(h, 0.f);
  unsigned short hi = f2bf(hr);
  oh[(size_t)w * 192 + lane] = hi;
  ol[(size_t)w * 192 + lane] = f2bf(hr - bf2f(hi));
}

// ---------------- edge MLP, CSR order ----------------

__global__ __launch_bounds__(256)
void edge_mlp_csr(const int* __restrict__ rowstart, const int2* __restrict__ csr_pack,
                  const unsigned short* __restrict__ Pb, const float* __restrict__ Qf,
                  const float* __restrict__ wm2, const float* __restrict__ bm2v,
                  float* __restrict__ out) {
  int wv = (blockIdx.x * 256 + threadIdx.x) >> 6;
  if (wv >= N_NODES) return;
  int lane = threadIdx.x & 63;
  int grp = lane >> 4, l = lane & 15;
  int beg = rowstart[wv], end = rowstart[wv + 1];
  if (beg == end) return;
  float4 q = *(const float4*)&Qf[(size_t)wv * 64 + l * 4];
  float4 w = *(const float4*)&wm2[l * 4];
  float b2 = bm2v[0];
  for (int i = beg + grp; i < end; i += 4) {
    int2 pk = csr_pack[i];
    int s = pk.x;
    int eid = pk.y;
    uint2 pu = *(const uint2*)&Pb[(size_t)s * 64 + l * 4];
    float p0 = bfraw(pu.x << 16);
    float p1 = bfraw(pu.x & 0xFFFF0000u);
    float p2 = bfraw(pu.y << 16);
    float p3 = bfraw(pu.y & 0xFFFF0000u);
    float h0 = fmaxf(p0 + q.x, 0.f);
    float h1 = fmaxf(p1 + q.y, 0.f);
    float h2 = fmaxf(p2 + q.z, 0.f);
    float h3 = fmaxf(p3 + q.w, 0.f);
    float part = h0 * w.x + h1 * w.y + h2 * w.z + h3 * w.w;
    part += __shfl_xor(part, 1);
    part += __shfl_xor(part, 2);
    part += __shfl_xor(part, 4);
    part += __shfl_xor(part, 8);
    if (l == 0) out[eid] = part + b2;
  }
}

// ---------------- launch ----------------

extern "C" void kernel_launch(void* const* d_in, const int* in_sizes, int n_in,
                              void* d_out, int out_size, void* d_ws, size_t ws_size,
                              hipStream_t stream) {
  (void)in_sizes; (void)n_in; (void)out_size; (void)ws_size;
  const float* x   = (const float*)d_in[0];
  const int*   src = (const int*)d_in[1];
  const int*   dst = (const int*)d_in[2];
  const float* Wl0 = (const float*)d_in[3];
  const float* bl0 = (const float*)d_in[4];
  const float* Wr0 = (const float*)d_in[5];
  const float* Wl1 = (const float*)d_in[6];
  const float* bl1 = (const float*)d_in[7];
  const float* Wr1 = (const float*)d_in[8];
  const float* Wl2 = (const float*)d_in[9];
  const float* bl2 = (const float*)d_in[10];
  const float* Wr2 = (const float*)d_in[11];
  const float* Wm1 = (const float*)d_in[12];
  const float* bm1 = (const float*)d_in[13];
  const float* Wm2 = (const float*)d_in[14];
  const float* bm2 = (const float*)d_in[15];
  float* out = (float*)d_out;

  char* ws = (char*)d_ws;
  size_t off = 0;
  auto take = [&](size_t bytes) {
    char* p = ws + off;
    off = (off + bytes + 255) & ~(size_t)255;
    return p;
  };
  int*   deg      = (int*)take((size_t)2 * N_NODES * 4);   // deg | cursor adjacent
  int*   cursor   = deg + N_NODES;
  int*   rowstart = (int*)take((size_t)(N_NODES + 1) * 4);
  int*   bsum     = (int*)take((size_t)SCAN_BLOCKS * 4);
  int*   boff     = (int*)take((size_t)SCAN_BLOCKS * 4);
  int2*  csr_pack = (int2*)take((size_t)N_EDGES * 8);
  // xh/xl: [N,192] bf16 node-embedding hi/lo; the first 12.8 MB of each also
  // serves (earlier, sequentially) as the [N,128] hi/lo split of the input x.
  unsigned short* xh = (unsigned short*)take((size_t)N_NODES * 192 * 2);
  unsigned short* xl = (unsigned short*)take((size_t)N_NODES * 192 * 2);
  unsigned short* y_nb = (unsigned short*)take((size_t)N_NODES * 64 * 2);  // also P
  float* y_rt     = (float*)take((size_t)N_NODES * 64 * 4);                 // also Q
  unsigned short* W0h = (unsigned short*)take((size_t)128 * 192 * 2);
  unsigned short* W0l = (unsigned short*)take((size_t)128 * 192 * 2);
  unsigned short* W1h = (unsigned short*)take((size_t)128 * 192 * 2);
  unsigned short* W1l = (unsigned short*)take((size_t)128 * 192 * 2);
  unsigned short* W2h = (unsigned short*)take((size_t)128 * 192 * 2);
  unsigned short* W2l = (unsigned short*)take((size_t)128 * 192 * 2);
  unsigned short* Wmh = (unsigned short*)take((size_t)128 * 192 * 2);
  unsigned short* Wml = (unsigned short*)take((size_t)128 * 192 * 2);

  hipMemsetAsync(deg, 0, (size_t)2 * N_NODES * 4, stream);

  int edge_grid = (N_EDGES + 255) / 256;
  count_deg<<<edge_grid, 256, 0, stream>>>(dst, deg);
  k_blocksum<<<SCAN_BLOCKS, 256, 0, stream>>>(deg, bsum);
  k_scanb<<<1, 256, 0, stream>>>(bsum, boff, rowstart);
  k_local<<<SCAN_BLOCKS, 256, 0, stream>>>(deg, boff, rowstart);
  scatter_edges<<<edge_grid, 256, 0, stream>>>(src, dst, rowstart, cursor, csr_pack);

  // input + weight hi/lo splits
  conv_x<<<(N_NODES * IN_CH / 8 + 255) / 256, 256, 0, stream>>>(x, xh, xl);  // [N,128] layout
  convW<<<128, 128, 0, stream>>>(Wl0, Wr0, IN_CH, 128, W0h, W0l);
  convW<<<128,  64, 0, stream>>>(Wl1, Wr1, HID,   64, W1h, W1l);
  convW<<<128,  64, 0, stream>>>(Wl2, Wr2, HID,   64, W2h, W2l);
  convW<<<128, 192, 0, stream>>>(Wm1, Wm1 + 192, 384, 192, Wmh, Wml);

  int gemm_grid = (N_NODES + 63) / 64;  // 782
  int node_waves_grid = (N_NODES * 64) / 256;  // 12500
  // layer 0 (A = x split, [N,128])
  gemm_mfma<<<gemm_grid, 256, 0, stream>>>(xh, xl, 128, 128, W0h, W0l, bl0, y_nb, y_rt);
  agg_fuse<<<node_waves_grid, 256, 0, stream>>>(y_nb, y_rt, rowstart, csr_pack, xh + 0, xl + 0);
  // layer 1 (A = xcat cols 0..63, ld 192)
  gemm_mfma<<<gemm_grid, 256, 0, stream>>>(xh, xl, 192, 64, W1h, W1l, bl1, y_nb, y_rt);
  agg_fuse<<<node_waves_grid, 256, 0, stream>>>(y_nb, y_rt, rowstart, csr_pack, xh + 64, xl + 64);
  // layer 2 (A = xcat cols 64..127)
  gemm_mfma<<<gemm_grid, 256, 0, stream>>>(xh + 64, xl + 64, 192, 64, W2h, W2l, bl2, y_nb, y_rt);
  agg_fuse<<<node_waves_grid, 256, 0, stream>>>(y_nb, y_rt, rowstart, csr_pack, xh + 128, xl + 128);
  // P (bf16) | Q + bm1 (fp32), K = 192
  gemm_mfma<<<gemm_grid, 256, 0, stream>>>(xh, xl, 192, 192, Wmh, Wml, bm1, y_nb, y_rt);
  edge_mlp_csr<<<node_waves_grid, 256, 0, stream>>>(rowstart, csr_pack, y_nb, y_rt, Wm2, bm2, out);
}

// Round 6
// 344.028 us; speedup vs baseline: 1.2245x; 1.0669x over previous
//
#include <hip/hip_runtime.h>

#define N_NODES 50000
#define N_EDGES 800000
#define IN_CH   128
#define HID     64
#define SCAN_BLOCKS ((N_NODES + 255) / 256)   // 196

typedef __attribute__((ext_vector_type(8))) short bf16x8;
typedef __attribute__((ext_vector_type(4))) float f32x4;

// ---------------- bf16 helpers ----------------

__device__ inline float bfraw(unsigned int bits) {
  float f; __builtin_memcpy(&f, &bits, 4); return f;
}
__device__ inline float bf2f(unsigned short u) {
  return bfraw(((unsigned int)u) << 16);
}
__device__ inline unsigned short f2bf(float f) {
  unsigned int x; __builtin_memcpy(&x, &f, 4);
  return (unsigned short)((x + 0x7FFFu + ((x >> 16) & 1u)) >> 16);
}

// ---------------- CSR build ----------------

__global__ __launch_bounds__(256) void count_deg(const int* __restrict__ dst,
                                                 int* __restrict__ deg) {
  int e = blockIdx.x * 256 + threadIdx.x;
  if (e < N_EDGES) atomicAdd(&deg[dst[e]], 1);
}

__global__ __launch_bounds__(256) void k_blocksum(const int* __restrict__ deg,
                                                  int* __restrict__ bsum) {
  int t = threadIdx.x, lane = t & 63, wid = t >> 6;
  int i = blockIdx.x * 256 + t;
  int v = (i < N_NODES) ? deg[i] : 0;
#pragma unroll
  for (int d = 32; d > 0; d >>= 1) v += __shfl_down(v, d);
  __shared__ int ws[4];
  if (lane == 0) ws[wid] = v;
  __syncthreads();
  if (t == 0) bsum[blockIdx.x] = ws[0] + ws[1] + ws[2] + ws[3];
}

__global__ __launch_bounds__(256) void k_scanb(const int* __restrict__ bsum,
                                               int* __restrict__ boff,
                                               int* __restrict__ rowstart) {
  int t = threadIdx.x, lane = t & 63, wid = t >> 6;
  int v = (t < SCAN_BLOCKS) ? bsum[t] : 0;
  int orig = v;
#pragma unroll
  for (int d = 1; d < 64; d <<= 1) {
    int u = __shfl_up(v, d);
    if (lane >= d) v += u;
  }
  __shared__ int ws[4];
  if (lane == 63) ws[wid] = v;
  __syncthreads();
  int off = 0;
  for (int j = 0; j < wid; ++j) off += ws[j];
  if (t < SCAN_BLOCKS) boff[t] = v - orig + off;
  if (t == 0) rowstart[N_NODES] = N_EDGES;
}

__global__ __launch_bounds__(256) void k_local(const int* __restrict__ deg,
                                               const int* __restrict__ boff,
                                               int* __restrict__ rowstart) {
  int t = threadIdx.x, lane = t & 63, wid = t >> 6;
  int i = blockIdx.x * 256 + t;
  int orig = (i < N_NODES) ? deg[i] : 0;
  int v = orig;
#pragma unroll
  for (int d = 1; d < 64; d <<= 1) {
    int u = __shfl_up(v, d);
    if (lane >= d) v += u;
  }
  __shared__ int ws[4];
  if (lane == 63) ws[wid] = v;
  __syncthreads();
  int off = boff[blockIdx.x];
  for (int j = 0; j < wid; ++j) off += ws[j];
  if (i < N_NODES) rowstart[i] = v - orig + off;
}

// one random 8B store per edge: (src, eid) packed
__global__ __launch_bounds__(256) void scatter_edges(const int* __restrict__ src,
                                                     const int* __restrict__ dst,
                                                     const int* __restrict__ rowstart,
                                                     int* __restrict__ cursor,
                                                     int2* __restrict__ csr_pack) {
  int e = blockIdx.x * 256 + threadIdx.x;
  if (e < N_EDGES) {
    int d = dst[e];
    int pos = atomicAdd(&cursor[d], 1);
    csr_pack[rowstart[d] + pos] = make_int2(src[e], e);
  }
}

// ---------------- fp32 -> bf16 hi/lo split ----------------

__global__ __launch_bounds__(256) void conv_x(const float* __restrict__ x,
                                              unsigned short* __restrict__ xh,
                                              unsigned short* __restrict__ xl) {
  size_t base = ((size_t)blockIdx.x * 256 + threadIdx.x) * 8;
  float4 a = *(const float4*)&x[base];
  float4 b = *(const float4*)&x[base + 4];
  float v[8] = {a.x, a.y, a.z, a.w, b.x, b.y, b.z, b.w};
  unsigned short h[8], l[8];
#pragma unroll
  for (int j = 0; j < 8; ++j) {
    h[j] = f2bf(v[j]);
    l[j] = f2bf(v[j] - bf2f(h[j]));
  }
  uint4 uh = make_uint4((unsigned)h[0] | ((unsigned)h[1] << 16),
                        (unsigned)h[2] | ((unsigned)h[3] << 16),
                        (unsigned)h[4] | ((unsigned)h[5] << 16),
                        (unsigned)h[6] | ((unsigned)h[7] << 16));
  uint4 ul = make_uint4((unsigned)l[0] | ((unsigned)l[1] << 16),
                        (unsigned)l[2] | ((unsigned)l[3] << 16),
                        (unsigned)l[4] | ((unsigned)l[5] << 16),
                        (unsigned)l[6] | ((unsigned)l[7] << 16));
  *(uint4*)&xh[base] = uh;
  *(uint4*)&xl[base] = ul;
}

__global__ __launch_bounds__(256) void convW(const float* __restrict__ Wa,
                                             const float* __restrict__ Wb, int ldW, int K,
                                             unsigned short* __restrict__ Bh,
                                             unsigned short* __restrict__ Bl) {
  int r = blockIdx.x;       // 0..127
  int k = threadIdx.x;      // 0..K-1 (blockDim == K)
  const float* wsrc = (r < 64) ? (Wa + (size_t)r * ldW) : (Wb + (size_t)(r - 64) * ldW);
  float v = wsrc[k];
  unsigned short hi = f2bf(v);
  Bh[(size_t)r * K + k] = hi;
  Bl[(size_t)r * K + k] = f2bf(v - bf2f(hi));
}

// ---------------- MFMA dual GEMM ----------------
// out cols 0..63  -> outA bf16 (= H @ Wa^T), cols 64..127 -> outB fp32 (= H @ Wb^T + bias)
// Compensated: acc += Ah*Bh + Al*Bh + Ah*Bl  (error ~2^-16 relative).

__global__ __launch_bounds__(256)
void gemm_mfma(const unsigned short* __restrict__ Ah, const unsigned short* __restrict__ Al,
               int ldA, int K,
               const unsigned short* __restrict__ Bh, const unsigned short* __restrict__ Bl,
               const float* __restrict__ bias,
               unsigned short* __restrict__ outA, float* __restrict__ outB) {
  int t = threadIdx.x;
  int lane = t & 63, wave = t >> 6;
  int r0 = blockIdx.x * 64;
  int col0 = wave * 32;
  int lrow = lane & 15;
  int kgrp = (lane >> 4) * 8;

  f32x4 z = {0.f, 0.f, 0.f, 0.f};
  f32x4 acc[4][2];
#pragma unroll
  for (int rt = 0; rt < 4; ++rt)
#pragma unroll
    for (int ct = 0; ct < 2; ++ct) acc[rt][ct] = z;

  int arow[4];
#pragma unroll
  for (int rt = 0; rt < 4; ++rt) {
    int r = r0 + rt * 16 + lrow;
    arow[rt] = (r < N_NODES) ? r : (N_NODES - 1);
  }
  int bcol0 = col0 + lrow;

  for (int k0 = 0; k0 < K; k0 += 32) {
    bf16x8 ah[4], al[4], bh[2], bl[2];
#pragma unroll
    for (int rt = 0; rt < 4; ++rt) {
      size_t o = (size_t)arow[rt] * ldA + k0 + kgrp;
      ah[rt] = *(const bf16x8*)(Ah + o);
      al[rt] = *(const bf16x8*)(Al + o);
    }
#pragma unroll
    for (int ct = 0; ct < 2; ++ct) {
      size_t o = (size_t)(bcol0 + ct * 16) * K + k0 + kgrp;
      bh[ct] = *(const bf16x8*)(Bh + o);
      bl[ct] = *(const bf16x8*)(Bl + o);
    }
#pragma unroll
    for (int rt = 0; rt < 4; ++rt)
#pragma unroll
      for (int ct = 0; ct < 2; ++ct) {
        acc[rt][ct] = __builtin_amdgcn_mfma_f32_16x16x32_bf16(ah[rt], bh[ct], acc[rt][ct], 0, 0, 0);
        acc[rt][ct] = __builtin_amdgcn_mfma_f32_16x16x32_bf16(al[rt], bh[ct], acc[rt][ct], 0, 0, 0);
        acc[rt][ct] = __builtin_amdgcn_mfma_f32_16x16x32_bf16(ah[rt], bl[ct], acc[rt][ct], 0, 0, 0);
      }
  }

  int crow = (lane >> 4) * 4;
#pragma unroll
  for (int ct = 0; ct < 2; ++ct) {
    int col = col0 + ct * 16 + lrow;
    bool isA = (col < 64);
    float bv = 0.f;
    if (!isA) bv = bias[col - 64];
#pragma unroll
    for (int rt = 0; rt < 4; ++rt) {
#pragma unroll
      for (int reg = 0; reg < 4; ++reg) {
        int row = r0 + rt * 16 + crow + reg;
        if (row < N_NODES) {
          float v = acc[rt][ct][reg];
          if (isA) outA[(size_t)row * 64 + col] = f2bf(v);
          else     outB[(size_t)row * 64 + (col - 64)] = v + bv;
        }
      }
    }
  }
}

// ---------------- aggregation (one wave per node) ----------------
// 16 lanes per row (uint2 = 8B/lane), 4 rows per load instruction, unroll x2
// -> 8 rows in flight per wave. Group-sum combined via shfl_xor(16/32), then
// redistributed so lane f holds feature f. Writes hi/lo bf16 (ld 192).

__global__ __launch_bounds__(256)
void agg_fuse(const unsigned short* __restrict__ y_nb, const float* __restrict__ y_rt,
              const int* __restrict__ rowstart, const int2* __restrict__ csr_pack,
              unsigned short* __restrict__ oh, unsigned short* __restrict__ ol) {
  int w = (blockIdx.x * 256 + threadIdx.x) >> 6;
  int lane = threadIdx.x & 63;
  if (w >= N_NODES) return;
  int beg = rowstart[w], end = rowstart[w + 1];
  int cnt = end - beg;
  int grp = lane >> 4;      // 0..3: which row within a quad
  int l16 = lane & 15;      // feature pair group: features 4*l16 .. 4*l16+3
  float s0 = 0.f, s1 = 0.f, s2 = 0.f, s3 = 0.f;

  int i = 0;
  for (; i + 8 <= cnt; i += 8) {
    int na = csr_pack[beg + i + grp].x;
    int nb = csr_pack[beg + i + 4 + grp].x;
    uint2 a = *(const uint2*)&y_nb[(size_t)na * 64 + l16 * 4];
    uint2 b = *(const uint2*)&y_nb[(size_t)nb * 64 + l16 * 4];
    s0 += bfraw(a.x << 16);          s1 += bfraw(a.x & 0xFFFF0000u);
    s2 += bfraw(a.y << 16);          s3 += bfraw(a.y & 0xFFFF0000u);
    s0 += bfraw(b.x << 16);          s1 += bfraw(b.x & 0xFFFF0000u);
    s2 += bfraw(b.y << 16);          s3 += bfraw(b.y & 0xFFFF0000u);
  }
  for (; i + 4 <= cnt; i += 4) {
    int na = csr_pack[beg + i + grp].x;
    uint2 a = *(const uint2*)&y_nb[(size_t)na * 64 + l16 * 4];
    s0 += bfraw(a.x << 16);          s1 += bfraw(a.x & 0xFFFF0000u);
    s2 += bfraw(a.y << 16);          s3 += bfraw(a.y & 0xFFFF0000u);
  }
  int rem = cnt - i;                 // 0..3
  if (grp < rem) {
    int na = csr_pack[beg + i + grp].x;
    uint2 a = *(const uint2*)&y_nb[(size_t)na * 64 + l16 * 4];
    s0 += bfraw(a.x << 16);          s1 += bfraw(a.x & 0xFFFF0000u);
    s2 += bfraw(a.y << 16);          s3 += bfraw(a.y & 0xFFFF0000u);
  }

  // combine the 4 row-groups (each lane then holds totals for features 4*l16+j)
  s0 += __shfl_xor(s0, 16); s0 += __shfl_xor(s0, 32);
  s1 += __shfl_xor(s1, 16); s1 += __shfl_xor(s1, 32);
  s2 += __shfl_xor(s2, 16); s2 += __shfl_xor(s2, 32);
  s3 += __shfl_xor(s3, 16); s3 += __shfl_xor(s3, 32);

  // redistribute: lane f needs feature f = 4*(f>>2) + (f&3), held at lane (f>>2)
  int srcl = lane >> 2;
  float t0 = __shfl(s0, srcl);
  float t1 = __shfl(s1, srcl);
  float t2 = __shfl(s2, srcl);
  float t3 = __shfl(s3, srcl);
  int j = lane & 3;
  float s = (j == 0) ? t0 : (j == 1) ? t1 : (j == 2) ? t2 : t3;

  float deg = (float)cnt;
  float inv = 1.0f / fmaxf(deg, 1.0f);
  float h = s * inv + y_rt[(size_t)w * 64 + lane];
  float hr = fmaxf(h, 0.f);
  unsigned short hi = f2bf(hr);
  oh[(size_t)w * 192 + lane] = hi;
  ol[(size_t)w * 192 + lane] = f2bf(hr - bf2f(hi));
}

// ---------------- edge MLP, CSR order ----------------

__global__ __launch_bounds__(256)
void edge_mlp_csr(const int* __restrict__ rowstart, const int2* __restrict__ csr_pack,
                  const unsigned short* __restrict__ Pb, const float* __restrict__ Qf,
                  const float* __restrict__ wm2, const float* __restrict__ bm2v,
                  float* __restrict__ out) {
  int wv = (blockIdx.x * 256 + threadIdx.x) >> 6;
  if (wv >= N_NODES) return;
  int lane = threadIdx.x & 63;
  int grp = lane >> 4, l = lane & 15;
  int beg = rowstart[wv], end = rowstart[wv + 1];
  if (beg == end) return;
  float4 q = *(const float4*)&Qf[(size_t)wv * 64 + l * 4];
  float4 w = *(const float4*)&wm2[l * 4];
  float b2 = bm2v[0];
  for (int i = beg + grp; i < end; i += 4) {
    int2 pk = csr_pack[i];
    int s = pk.x;
    int eid = pk.y;
    uint2 pu = *(const uint2*)&Pb[(size_t)s * 64 + l * 4];
    float p0 = bfraw(pu.x << 16);
    float p1 = bfraw(pu.x & 0xFFFF0000u);
    float p2 = bfraw(pu.y << 16);
    float p3 = bfraw(pu.y & 0xFFFF0000u);
    float h0 = fmaxf(p0 + q.x, 0.f);
    float h1 = fmaxf(p1 + q.y, 0.f);
    float h2 = fmaxf(p2 + q.z, 0.f);
    float h3 = fmaxf(p3 + q.w, 0.f);
    float part = h0 * w.x + h1 * w.y + h2 * w.z + h3 * w.w;
    part += __shfl_xor(part, 1);
    part += __shfl_xor(part, 2);
    part += __shfl_xor(part, 4);
    part += __shfl_xor(part, 8);
    if (l == 0) out[eid] = part + b2;
  }
}

// ---------------- launch ----------------

extern "C" void kernel_launch(void* const* d_in, const int* in_sizes, int n_in,
                              void* d_out, int out_size, void* d_ws, size_t ws_size,
                              hipStream_t stream) {
  (void)in_sizes; (void)n_in; (void)out_size; (void)ws_size;
  const float* x   = (const float*)d_in[0];
  const int*   src = (const int*)d_in[1];
  const int*   dst = (const int*)d_in[2];
  const float* Wl0 = (const float*)d_in[3];
  const float* bl0 = (const float*)d_in[4];
  const float* Wr0 = (const float*)d_in[5];
  const float* Wl1 = (const float*)d_in[6];
  const float* bl1 = (const float*)d_in[7];
  const float* Wr1 = (const float*)d_in[8];
  const float* Wl2 = (const float*)d_in[9];
  const float* bl2 = (const float*)d_in[10];
  const float* Wr2 = (const float*)d_in[11];
  const float* Wm1 = (const float*)d_in[12];
  const float* bm1 = (const float*)d_in[13];
  const float* Wm2 = (const float*)d_in[14];
  const float* bm2 = (const float*)d_in[15];
  float* out = (float*)d_out;

  char* ws = (char*)d_ws;
  size_t off = 0;
  auto take = [&](size_t bytes) {
    char* p = ws + off;
    off = (off + bytes + 255) & ~(size_t)255;
    return p;
  };
  int*   deg      = (int*)take((size_t)2 * N_NODES * 4);   // deg | cursor adjacent
  int*   cursor   = deg + N_NODES;
  int*   rowstart = (int*)take((size_t)(N_NODES + 1) * 4);
  int*   bsum     = (int*)take((size_t)SCAN_BLOCKS * 4);
  int*   boff     = (int*)take((size_t)SCAN_BLOCKS * 4);
  int2*  csr_pack = (int2*)take((size_t)N_EDGES * 8);
  unsigned short* xh = (unsigned short*)take((size_t)N_NODES * 192 * 2);
  unsigned short* xl = (unsigned short*)take((size_t)N_NODES * 192 * 2);
  unsigned short* y_nb = (unsigned short*)take((size_t)N_NODES * 64 * 2);  // also P
  float* y_rt     = (float*)take((size_t)N_NODES * 64 * 4);                 // also Q
  unsigned short* W0h = (unsigned short*)take((size_t)128 * 192 * 2);
  unsigned short* W0l = (unsigned short*)take((size_t)128 * 192 * 2);
  unsigned short* W1h = (unsigned short*)take((size_t)128 * 192 * 2);
  unsigned short* W1l = (unsigned short*)take((size_t)128 * 192 * 2);
  unsigned short* W2h = (unsigned short*)take((size_t)128 * 192 * 2);
  unsigned short* W2l = (unsigned short*)take((size_t)128 * 192 * 2);
  unsigned short* Wmh = (unsigned short*)take((size_t)128 * 192 * 2);
  unsigned short* Wml = (unsigned short*)take((size_t)128 * 192 * 2);

  hipMemsetAsync(deg, 0, (size_t)2 * N_NODES * 4, stream);

  int edge_grid = (N_EDGES + 255) / 256;
  count_deg<<<edge_grid, 256, 0, stream>>>(dst, deg);
  k_blocksum<<<SCAN_BLOCKS, 256, 0, stream>>>(deg, bsum);
  k_scanb<<<1, 256, 0, stream>>>(bsum, boff, rowstart);
  k_local<<<SCAN_BLOCKS, 256, 0, stream>>>(deg, boff, rowstart);
  scatter_edges<<<edge_grid, 256, 0, stream>>>(src, dst, rowstart, cursor, csr_pack);

  // input + weight hi/lo splits
  conv_x<<<(N_NODES * IN_CH / 8 + 255) / 256, 256, 0, stream>>>(x, xh, xl);
  convW<<<128, 128, 0, stream>>>(Wl0, Wr0, IN_CH, 128, W0h, W0l);
  convW<<<128,  64, 0, stream>>>(Wl1, Wr1, HID,   64, W1h, W1l);
  convW<<<128,  64, 0, stream>>>(Wl2, Wr2, HID,   64, W2h, W2l);
  convW<<<128, 192, 0, stream>>>(Wm1, Wm1 + 192, 384, 192, Wmh, Wml);

  int gemm_grid = (N_NODES + 63) / 64;  // 782
  int node_waves_grid = (N_NODES * 64) / 256;  // 12500
  // layer 0 (A = x split, [N,128])
  gemm_mfma<<<gemm_grid, 256, 0, stream>>>(xh, xl, 128, 128, W0h, W0l, bl0, y_nb, y_rt);
  agg_fuse<<<node_waves_grid, 256, 0, stream>>>(y_nb, y_rt, rowstart, csr_pack, xh + 0, xl + 0);
  // layer 1 (A = xcat cols 0..63, ld 192)
  gemm_mfma<<<gemm_grid, 256, 0, stream>>>(xh, xl, 192, 64, W1h, W1l, bl1, y_nb, y_rt);
  agg_fuse<<<node_waves_grid, 256, 0, stream>>>(y_nb, y_rt, rowstart, csr_pack, xh + 64, xl + 64);
  // layer 2 (A = xcat cols 64..127)
  gemm_mfma<<<gemm_grid, 256, 0, stream>>>(xh + 64, xl + 64, 192, 64, W2h, W2l, bl2, y_nb, y_rt);
  agg_fuse<<<node_waves_grid, 256, 0, stream>>>(y_nb, y_rt, rowstart, csr_pack, xh + 128, xl + 128);
  // P (bf16) | Q + bm1 (fp32), K = 192
  gemm_mfma<<<gemm_grid, 256, 0, stream>>>(xh, xl, 192, 192, Wmh, Wml, bm1, y_nb, y_rt);
  edge_mlp_csr<<<node_waves_grid, 256, 0, stream>>>(rowstart, csr_pack, y_nb, y_rt, Wm2, bm2, out);
}